// Round 4
// baseline (744.442 us; speedup 1.0000x reference)
//
#include <hip/hip_runtime.h>
#include <stdint.h>

typedef __attribute__((ext_vector_type(8))) short short8;
typedef __attribute__((ext_vector_type(4))) float f32x4;

__device__ __forceinline__ unsigned short f2bf(float x) {
  unsigned int u = __float_as_uint(x);
  u += 0x7fffu + ((u >> 16) & 1u);
  return (unsigned short)(u >> 16);
}
__device__ __forceinline__ float bf2f(unsigned short h) {
  return __uint_as_float(((unsigned int)h) << 16);
}

#define GLOAD16(gsrc, ldst)                                              \
  __builtin_amdgcn_global_load_lds(                                      \
      (const __attribute__((address_space(1))) void*)(gsrc),             \
      (__attribute__((address_space(3))) void*)(ldst), 16, 0, 0)

// ---------- split fp32 -> (hi, lo) bf16 ----------
__global__ __launch_bounds__(256) void split_pair_kernel(
    const float* __restrict__ in, unsigned short* __restrict__ h,
    unsigned short* __restrict__ l) {
  size_t i = (size_t)blockIdx.x * 256 + threadIdx.x;
  float4 v = ((const float4*)in)[i];
  unsigned short h0 = f2bf(v.x), h1 = f2bf(v.y), h2 = f2bf(v.z), h3 = f2bf(v.w);
  ((ushort4*)h)[i] = make_ushort4(h0, h1, h2, h3);
  ((ushort4*)l)[i] = make_ushort4(f2bf(v.x - bf2f(h0)), f2bf(v.y - bf2f(h1)),
                                  f2bf(v.z - bf2f(h2)), f2bf(v.w - bf2f(h3)));
}

// ---------- transpose W [K][N] fp32 -> hi/lo bf16 [N][K] ----------
__global__ __launch_bounds__(256) void transpose_split_kernel(
    const float* __restrict__ W, unsigned short* __restrict__ hT,
    unsigned short* __restrict__ lT, int Kd, int Nd) {
  __shared__ float tile[32][33];
  int r = threadIdx.x >> 3;
  int c = (threadIdx.x & 7) * 4;
  int k0 = blockIdx.y * 32, n0 = blockIdx.x * 32;
  float4 v = *(const float4*)&W[(size_t)(k0 + r) * Nd + n0 + c];
  tile[r][c] = v.x; tile[r][c + 1] = v.y; tile[r][c + 2] = v.z; tile[r][c + 3] = v.w;
  __syncthreads();
  float x0 = tile[c + 0][r], x1 = tile[c + 1][r], x2 = tile[c + 2][r], x3 = tile[c + 3][r];
  unsigned short h0 = f2bf(x0), h1 = f2bf(x1), h2 = f2bf(x2), h3 = f2bf(x3);
  size_t o = (size_t)(n0 + r) * Kd + k0 + c;
  *(ushort4*)&hT[o] = make_ushort4(h0, h1, h2, h3);
  *(ushort4*)&lT[o] = make_ushort4(f2bf(x0 - bf2f(h0)), f2bf(x1 - bf2f(h1)),
                                   f2bf(x2 - bf2f(h2)), f2bf(x3 - bf2f(h3)));
}

// =====================================================================
// 8-phase 256x256 BK=64 bf16 NT GEMM, K-segmented operands.
// A[m][k] = Aseg[k>>10][m*lda + (k&1023)], same for B. 8 waves (2Mx4N),
// per-wave C = 128x64, per-phase C-quadrant 64x32 (qr,qc)=(0,0),(0,1),(1,0),(1,1).
// Half-tiles grouped by QUADRANT USAGE so they free mid-tile:
//   HA0 = A rowgroups {0-3,8-11}   read ph0,ph1 -> free after ph1
//   HA1 = A rowgroups {4-7,12-15}  read ph2,ph3
//   HB0 = B rowgroups {0,1,4,5,8,9,12,13}  read ph0,ph2
//   HB1 = B rowgroups {2,3,6,7,10,11,14,15} read ph1,ph3
// Staging: ph0 HA1(t+1)->nbuf, ph1 HB1(t+1)->nbuf, ph2 HA0(t+2)->buf,
//          ph3 HB0(t+2)->buf. vmcnt placed AFTER MFMA, before the final
//          barrier, gating NEXT phase's ds_reads: steady (6,8,8,6).
// LDS 128KB = 2buf x (A 32KB + B 32KB), subtile 16rows x 32k = 1KB,
// fragment-linear (lane l owns bytes [16l,16l+16)).
// =====================================================================
#define LDA4(BUF, QR)                                                        \
  _Pragma("unroll") for (int _i = 0; _i < 4; ++_i)                           \
  _Pragma("unroll") for (int _k = 0; _k < 2; ++_k)                           \
      areg[_i][_k] = *(const short8*)(smem + (BUF) * 65536 +                 \
          ((wm * 8 + (QR) * 4 + _i) * 2 + _k) * 1024 + lane * 16);

#define LDB2(BUF, QC)                                                        \
  _Pragma("unroll") for (int _j = 0; _j < 2; ++_j)                           \
  _Pragma("unroll") for (int _k = 0; _k < 2; ++_k)                           \
      breg[_j][_k] = *(const short8*)(smem + (BUF) * 65536 + 32768 +         \
          ((wn * 4 + (QC) * 2 + _j) * 2 + _k) * 1024 + lane * 16);

#define MMA16(QR, QC)                                                        \
  __builtin_amdgcn_s_setprio(1);                                             \
  _Pragma("unroll") for (int _i = 0; _i < 4; ++_i)                           \
  _Pragma("unroll") for (int _j = 0; _j < 2; ++_j)                           \
  _Pragma("unroll") for (int _k = 0; _k < 2; ++_k)                           \
      acc[(QR) * 4 + _i][(QC) * 2 + _j] =                                    \
          __builtin_amdgcn_mfma_f32_16x16x32_bf16(                           \
              areg[_i][_k], breg[_j][_k], acc[(QR) * 4 + _i][(QC) * 2 + _j], \
              0, 0, 0);                                                      \
  __builtin_amdgcn_s_setprio(0);

__device__ __forceinline__ const unsigned short* segsel(
    const unsigned short* s0, const unsigned short* s1,
    const unsigned short* s2, const unsigned short* s3, int seg) {
  return seg == 0 ? s0 : seg == 1 ? s1 : seg == 2 ? s2 : s3;
}

// HALF: 0=HA0, 1=HA1, 2=HB0, 3=HB1. 2 gloads (k-halves of one rowgroup).
#define STAGE(BUF, HALF, KT)                                                 \
  {                                                                          \
    const int _seg = (KT) >> 4;                                              \
    const int _ko = ((KT) & 15) * 64;                                        \
    const unsigned short* _sb = ((HALF) < 2)                                 \
        ? segsel(A0, A1, A2, A3, _seg) : segsel(B0, B1, B2, B3, _seg);       \
    const size_t _src = (((HALF) < 2) ? rowOffA[(HALF)] : rowOffB[(HALF)-2]) \
        + (size_t)_ko;                                                       \
    char* _d = smem + (BUF) * 65536 +                                        \
        (((HALF) < 2) ? dstA[(HALF)] : dstB[(HALF)-2]);                      \
    GLOAD16(_sb + _src, _d);                                                 \
    GLOAD16(_sb + _src + 32, _d + 1024);                                     \
  }

#define VM(N) asm volatile("s_waitcnt vmcnt(" #N ")" ::: "memory")
#define BARSYNC __builtin_amdgcn_s_barrier()
#define LGKM0                                                \
  do {                                                       \
    asm volatile("s_waitcnt lgkmcnt(0)" ::: "memory");       \
    __builtin_amdgcn_sched_barrier(0);                       \
  } while (0)

template <int OM>  // 0: fp32 out; 3: fused QKV epilogue
__global__ __launch_bounds__(512, 2) void g8_kernel(
    const unsigned short* A0, const unsigned short* A1,
    const unsigned short* A2, const unsigned short* A3,
    const unsigned short* B0, const unsigned short* B1,
    const unsigned short* B2, const unsigned short* B3,
    int K, int lda, int ldb, float* outF, int ldo,
    const float* bq, const float* bk, const float* bv,
    unsigned short* qh, unsigned short* ql, unsigned short* kh,
    unsigned short* kl, unsigned short* vT) {
  __shared__ __attribute__((aligned(16))) char smem[131072];
  const int t = threadIdx.x, wid = t >> 6, lane = t & 63;
  const int wm = wid >> 2, wn = wid & 3;
  const int lr = lane & 15, lk0 = (lane >> 4) * 8;
  const int m0 = blockIdx.y * 256, n0 = blockIdx.x * 256;

  // per-wave staging rowgroups for each half-tile
  const int rgA0 = wid + ((wid >> 2) << 2);            // {0-3,8-11}
  const int rgA1 = 4 + rgA0;                           // {4-7,12-15}
  const int rgB0 = (wid & 1) + ((wid >> 1) << 2);      // {0,1,4,5,8,9,12,13}
  const int rgB1 = 2 + rgB0;                           // {2,3,6,7,10,11,14,15}
  size_t rowOffA[2] = {(size_t)(m0 + rgA0 * 16 + lr) * lda + lk0,
                       (size_t)(m0 + rgA1 * 16 + lr) * lda + lk0};
  size_t rowOffB[2] = {(size_t)(n0 + rgB0 * 16 + lr) * ldb + lk0,
                       (size_t)(n0 + rgB1 * 16 + lr) * ldb + lk0};
  const int dstA[2] = {rgA0 * 2048, rgA1 * 2048};
  const int dstB[2] = {32768 + rgB0 * 2048, 32768 + rgB1 * 2048};

  const int NT = K >> 6;
  f32x4 acc[8][4] = {};
  short8 areg[4][2], breg[2][2];

  // prologue: HA0(0), HB0(0), HA1(0), HB1(0), HA0(1), HB0(1); land first 2.
  STAGE(0, 0, 0);
  STAGE(0, 2, 0);
  STAGE(0, 1, 0);
  STAGE(0, 3, 0);
  STAGE(1, 0, 1);
  STAGE(1, 2, 1);
  VM(8);
  BARSYNC;

#pragma unroll 1
  for (int tt = 0; tt < NT; ++tt) {
    const int buf = tt & 1, nbuf = buf ^ 1;
    const bool st1 = (tt + 1 < NT), st2 = (tt + 2 < NT);
    // ---- phase 0: quad(0,0); stage HA1(t+1)
    LDA4(buf, 0) LDB2(buf, 0)
    if (st1) STAGE(nbuf, 1, tt + 1);
    BARSYNC; LGKM0;
    MMA16(0, 0)
    if (st1) { VM(6); } else { VM(0); }
    BARSYNC;
    // ---- phase 1: quad(0,1); stage HB1(t+1)
    LDB2(buf, 1)
    if (st1) STAGE(nbuf, 3, tt + 1);
    BARSYNC; LGKM0;
    MMA16(0, 1)
    if (st1) { VM(8); }
    BARSYNC;
    // ---- phase 2: quad(1,0); stage HA0(t+2) into freed slot
    LDA4(buf, 1) LDB2(buf, 0)
    if (st2) STAGE(buf, 0, tt + 2);
    BARSYNC; LGKM0;
    MMA16(1, 0)
    if (st2) { VM(8); } else if (st1) { VM(6); }
    BARSYNC;
    // ---- phase 3: quad(1,1); stage HB0(t+2)
    LDB2(buf, 1)
    if (st2) STAGE(buf, 2, tt + 2);
    BARSYNC; LGKM0;
    MMA16(1, 1)
    if (st2) { VM(6); } else if (st1) { VM(4); }
    BARSYNC;
  }

  // epilogue: C/D frag layout col=lane&15, row=(lane>>4)*4+r
  const int or0 = (lane >> 4) * 4;
  if constexpr (OM == 0) {
#pragma unroll
    for (int rg = 0; rg < 8; ++rg)
#pragma unroll
      for (int cg = 0; cg < 4; ++cg)
#pragma unroll
        for (int r = 0; r < 4; ++r)
          outF[(size_t)(m0 + wm * 128 + rg * 16 + or0 + r) * ldo +
               (n0 + wn * 64 + cg * 16 + lr)] = acc[rg][cg][r];
  } else {
    const int nr = n0 >> 10;
#pragma unroll
    for (int rg = 0; rg < 8; ++rg)
#pragma unroll
      for (int cg = 0; cg < 4; ++cg)
#pragma unroll
        for (int r = 0; r < 4; ++r) {
          int row = m0 + wm * 128 + rg * 16 + or0 + r;
          int col = (n0 & 1023) + wn * 64 + cg * 16 + lr;
          float x = acc[rg][cg][r];
          if (nr == 0) {
            x += bq[col];
            unsigned short h = f2bf(x);
            qh[(size_t)row * 1024 + col] = h;
            ql[(size_t)row * 1024 + col] = f2bf(x - bf2f(h));
          } else if (nr == 1) {
            x += bk[col];
            unsigned short h = f2bf(x);
            kh[(size_t)row * 1024 + col] = h;
            kl[(size_t)row * 1024 + col] = f2bf(x - bf2f(h));
          } else {
            x += bv[col];
            vT[(size_t)col * 8192 + row] = f2bf(x);
          }
        }
  }
}

// ---------- row softmax: fp32 [4096] -> bf16 probs (in-place, pld stride) ----
__global__ __launch_bounds__(256) void softmax_rows_kernel(
    const float* Sm, unsigned short* P, int ncol, int pld) {
  const int t = threadIdx.x;
  const float* srow = Sm + (size_t)blockIdx.x * ncol;
  float4 v[4];
  float m = -3.4e38f;
#pragma unroll
  for (int i = 0; i < 4; ++i) {
    v[i] = ((const float4*)srow)[t + 256 * i];
    m = fmaxf(m, fmaxf(fmaxf(v[i].x, v[i].y), fmaxf(v[i].z, v[i].w)));
  }
#pragma unroll
  for (int off = 32; off >= 1; off >>= 1) m = fmaxf(m, __shfl_down(m, off));
  __shared__ float redm[4];
  if ((t & 63) == 0) redm[t >> 6] = m;
  __syncthreads();
  m = fmaxf(fmaxf(redm[0], redm[1]), fmaxf(redm[2], redm[3]));
  float s = 0.f;
#pragma unroll
  for (int i = 0; i < 4; ++i) {
    v[i].x = __expf(v[i].x - m);
    v[i].y = __expf(v[i].y - m);
    v[i].z = __expf(v[i].z - m);
    v[i].w = __expf(v[i].w - m);
    s += v[i].x + v[i].y + v[i].z + v[i].w;
  }
#pragma unroll
  for (int off = 32; off >= 1; off >>= 1) s += __shfl_down(s, off);
  __shared__ float reds[4];
  if ((t & 63) == 0) reds[t >> 6] = s;
  __syncthreads();
  s = reds[0] + reds[1] + reds[2] + reds[3];
  float inv = 1.f / s;
  unsigned short* prow = P + (size_t)blockIdx.x * pld;
#pragma unroll
  for (int i = 0; i < 4; ++i) {
    ushort4 o = make_ushort4(f2bf(v[i].x * inv), f2bf(v[i].y * inv),
                             f2bf(v[i].z * inv), f2bf(v[i].w * inv));
    ((ushort4*)prow)[t + 256 * i] = o;
  }
}

extern "C" void kernel_launch(void* const* d_in, const int* in_sizes, int n_in,
                              void* d_out, int out_size, void* d_ws, size_t ws_size,
                              hipStream_t stream) {
  const float* hs = (const float*)d_in[0];
  const float* Wq = (const float*)d_in[1];
  const float* bq = (const float*)d_in[2];
  const float* Wk = (const float*)d_in[3];
  const float* bk = (const float*)d_in[4];
  const float* Wv = (const float*)d_in[5];
  const float* bv = (const float*)d_in[6];
  float* out = (float*)d_out;

  constexpr int Ss = 4096, Hh = 1024;
  constexpr int Mm = 8192;
  char* ws = (char*)d_ws;
  const size_t MB = 1024 * 1024;

  // region A (live): qh,ql,kh,kl,vT (16MB each) = 80MB
  unsigned short* qh = (unsigned short*)(ws + 0 * MB);
  unsigned short* ql = (unsigned short*)(ws + 16 * MB);
  unsigned short* kh = (unsigned short*)(ws + 32 * MB);
  unsigned short* kl = (unsigned short*)(ws + 48 * MB);
  unsigned short* vT = (unsigned short*)(ws + 64 * MB);  // [1024][8192]
  // region B at +80MB: early = hs splits + weights; late = 64MB score slab
  char* rb = ws + 80 * MB;
  unsigned short* hs_h = (unsigned short*)(rb + 0 * MB);
  unsigned short* hs_l = (unsigned short*)(rb + 16 * MB);
  unsigned short* WhT = (unsigned short*)(rb + 32 * MB);  // [3072][1024]
  unsigned short* WlT = (unsigned short*)(rb + 38 * MB);
  float* Sf = (float*)rb;  // 64MB slab per batch (reused), P bf16 in-place

  // 1) splits
  split_pair_kernel<<<dim3(Mm * Hh / 1024), 256, 0, stream>>>(hs, hs_h, hs_l);
  transpose_split_kernel<<<dim3(32, 32), 256, 0, stream>>>(Wq, WhT, WlT, Hh, Hh);
  transpose_split_kernel<<<dim3(32, 32), 256, 0, stream>>>(
      Wk, WhT + (size_t)1024 * 1024, WlT + (size_t)1024 * 1024, Hh, Hh);
  transpose_split_kernel<<<dim3(32, 32), 256, 0, stream>>>(
      Wv, WhT + (size_t)2048 * 1024, WlT + (size_t)2048 * 1024, Hh, Hh);

  // 2) fused QKV projection: M=8192, N=3072, K=3072 (segs {h,l,h} x {Wh,Wh,Wl})
  g8_kernel<3><<<dim3(12, 32), 512, 0, stream>>>(
      hs_h, hs_l, hs_h, hs_h, WhT, WhT, WlT, WlT,
      3072, 1024, 1024, nullptr, 0, bq, bk, bv, qh, ql, kh, kl, vT);

  // 3) per batch: scores -> softmax(in-place, bf16) -> context
  for (int b = 0; b < 2; ++b) {
    const size_t tk = (size_t)b * Ss * Hh;
    // QK^T: K=3072 segs A={qh,ql,qh}, B={kh,kh,kl}
    g8_kernel<0><<<dim3(16, 16), 512, 0, stream>>>(
        qh + tk, ql + tk, qh + tk, qh + tk,
        kh + tk, kh + tk, kl + tk, kl + tk,
        3072, 1024, 1024, Sf, Ss, nullptr, nullptr, nullptr,
        nullptr, nullptr, nullptr, nullptr, nullptr);
    softmax_rows_kernel<<<dim3(Ss), 256, 0, stream>>>(
        Sf, (unsigned short*)Sf, Ss, 2 * Ss);
    // PV: A = P bf16 (ld 8192 shorts, segs +1024k), B = vT cols (ld 8192)
    const unsigned short* P0 = (const unsigned short*)Sf;
    const unsigned short* vb = vT + (size_t)b * Ss;
    g8_kernel<0><<<dim3(4, 16), 512, 0, stream>>>(
        P0, P0 + 1024, P0 + 2048, P0 + 3072,
        vb, vb + 1024, vb + 2048, vb + 3072,
        4096, 2 * Ss, Mm, out + tk, Hh, nullptr, nullptr, nullptr,
        nullptr, nullptr, nullptr, nullptr, nullptr);
  }
}